// Round 5
// baseline (899.629 us; speedup 1.0000x reference)
//
#include <hip/hip_runtime.h>
#include <cstdint>
#include <cstddef>

#define DIM 128
#define NEG_SLOPE 0.2f

// ---- bf16 helpers (manual, RNE) -------------------------------------------
__device__ __forceinline__ float bf_lo(uint u) { return __uint_as_float(u << 16); }
__device__ __forceinline__ float bf_hi(uint u) { return __uint_as_float(u & 0xffff0000u); }
__device__ __forceinline__ uint f2bf(float f) {
  uint u = __float_as_uint(f);
  return (u + 0x7fffu + ((u >> 16) & 1u)) >> 16;
}
__device__ __forceinline__ uint pack_bf2(float lo, float hi) {
  return f2bf(lo) | (f2bf(hi) << 16);
}
__device__ __forceinline__ float lrelu(float x) {
  return x >= 0.0f ? x : NEG_SLOPE * x;
}

// ---------------------------------------------------------------------------
// GEMM: Y_bf16[rows x 128] = X[rows x 128] @ W[128 x 128] (fp32 compute),
// fused epilogue: s_n[row] = dot(Y_fp32[row,:], att[0:128]).
// ---------------------------------------------------------------------------
__global__ __launch_bounds__(256) void gemm128_kernel(
    const float* __restrict__ X, const float* __restrict__ W,
    const float* __restrict__ att, ushort* __restrict__ Yb,
    float* __restrict__ s_n, int rows)
{
  __shared__ float Wl[128 * 128];
  __shared__ float Xl[32 * 128];
  int tid = threadIdx.x;
  {
    const float4* W4 = (const float4*)W;
    float4* Wl4 = (float4*)Wl;
#pragma unroll
    for (int i = 0; i < 16; ++i) Wl4[tid + i * 256] = W4[tid + i * 256];
  }
  int r0 = blockIdx.x * 32;
  int nrow = rows - r0; if (nrow > 32) nrow = 32;
  {
    const float4* X4 = (const float4*)(X + (size_t)r0 * DIM);
    float4* Xl4 = (float4*)Xl;
    for (int i = tid; i < nrow * 32; i += 256) Xl4[i] = X4[i];
  }
  __syncthreads();
  int rq = (tid >> 5) << 2;
  int dg = (tid & 31) << 2;
  float4 a0 = {0,0,0,0}, a1 = a0, a2 = a0, a3 = a0;
#pragma unroll 4
  for (int k = 0; k < 128; ++k) {
    float4 w = *(const float4*)&Wl[k * 128 + dg];
    float x0 = Xl[(rq + 0) * 128 + k];
    float x1 = Xl[(rq + 1) * 128 + k];
    float x2 = Xl[(rq + 2) * 128 + k];
    float x3 = Xl[(rq + 3) * 128 + k];
    a0.x = fmaf(x0, w.x, a0.x); a0.y = fmaf(x0, w.y, a0.y);
    a0.z = fmaf(x0, w.z, a0.z); a0.w = fmaf(x0, w.w, a0.w);
    a1.x = fmaf(x1, w.x, a1.x); a1.y = fmaf(x1, w.y, a1.y);
    a1.z = fmaf(x1, w.z, a1.z); a1.w = fmaf(x1, w.w, a1.w);
    a2.x = fmaf(x2, w.x, a2.x); a2.y = fmaf(x2, w.y, a2.y);
    a2.z = fmaf(x2, w.z, a2.z); a2.w = fmaf(x2, w.w, a2.w);
    a3.x = fmaf(x3, w.x, a3.x); a3.y = fmaf(x3, w.y, a3.y);
    a3.z = fmaf(x3, w.z, a3.z); a3.w = fmaf(x3, w.w, a3.w);
  }
  ushort4 h;
#define STORE_BF(acc, r) \
  if (r0 + (r) < rows) { \
    h.x = (ushort)f2bf(acc.x); h.y = (ushort)f2bf(acc.y); \
    h.z = (ushort)f2bf(acc.z); h.w = (ushort)f2bf(acc.w); \
    *(ushort4*)&Yb[(size_t)(r0 + (r)) * DIM + dg] = h; }
  STORE_BF(a0, rq + 0)
  STORE_BF(a1, rq + 1)
  STORE_BF(a2, rq + 2)
  STORE_BF(a3, rq + 3)
#undef STORE_BF
  float4 av = *(const float4*)&att[dg];
  float s0 = a0.x*av.x + a0.y*av.y + a0.z*av.z + a0.w*av.w;
  float s1 = a1.x*av.x + a1.y*av.y + a1.z*av.z + a1.w*av.w;
  float s2 = a2.x*av.x + a2.y*av.y + a2.z*av.z + a2.w*av.w;
  float s3 = a3.x*av.x + a3.y*av.y + a3.z*av.z + a3.w*av.w;
#pragma unroll
  for (int m = 16; m >= 1; m >>= 1) {
    s0 += __shfl_xor(s0, m, 64);
    s1 += __shfl_xor(s1, m, 64);
    s2 += __shfl_xor(s2, m, 64);
    s3 += __shfl_xor(s3, m, 64);
  }
  if ((tid & 31) == 0) {
    if (r0 + rq + 0 < rows) s_n[r0 + rq + 0] = s0;
    if (r0 + rq + 1 < rows) s_n[r0 + rq + 1] = s1;
    if (r0 + rq + 2 < rows) s_n[r0 + rq + 2] = s2;
    if (r0 + rq + 3 < rows) s_n[r0 + rq + 3] = s3;
  }
}

// ---------------------------------------------------------------------------
// se_kernel: wv2 = W @ att[D:] (recomputed per block in LDS), then
// s_e[e] = dot(traj[e,:], wv2); se_hw[e] = {s_e, hw[e]}. One wave per edge.
// ---------------------------------------------------------------------------
__global__ __launch_bounds__(256) void se_kernel(
    const float* __restrict__ traj, const float* __restrict__ W,
    const float* __restrict__ att, const float* __restrict__ hw,
    float* __restrict__ s_e, float2* __restrict__ se_hw, int M_)
{
  __shared__ float wv[128];
  int tid = threadIdx.x;
  if (tid < 128) {
    const float* wr = W + (size_t)tid * 128;
    float acc = 0.0f;
#pragma unroll 4
    for (int k = 0; k < 128; ++k) acc = fmaf(wr[k], att[DIM + k], acc);
    wv[tid] = acc;
  }
  __syncthreads();
  int e = blockIdx.x * 4 + (tid >> 6);
  int lane = tid & 63;
  if (e >= M_) return;
  const float* row = traj + (size_t)e * DIM;
  float v = row[lane] * wv[lane] + row[lane + 64] * wv[lane + 64];
#pragma unroll
  for (int d = 32; d > 0; d >>= 1) v += __shfl_down(v, d, 64);
  if (lane == 0) {
    s_e[e] = v;
    float2 g; g.x = v; g.y = hw[e];
    se_hw[e] = g;
  }
}

// ---------------------------------------------------------------------------
// Rank-fused histogram, 4 items/thread (8 atomics in flight).
// ---------------------------------------------------------------------------
__global__ void hist_rank_kernel(const int* __restrict__ node_idx,
                                 const int* __restrict__ edge_idx,
                                 int* __restrict__ ncnt, int* __restrict__ ecnt,
                                 int* __restrict__ r_n, int* __restrict__ r_e,
                                 int nnz)
{
  int j = (blockIdx.x * blockDim.x + threadIdx.x) * 4;
  if (j >= nnz) return;
  if (j + 4 <= nnz) {
    int4 e = *(const int4*)&edge_idx[j];
    int4 n = *(const int4*)&node_idx[j];
    int a0 = atomicAdd(&ecnt[e.x], 1);
    int a1 = atomicAdd(&ecnt[e.y], 1);
    int a2 = atomicAdd(&ecnt[e.z], 1);
    int a3 = atomicAdd(&ecnt[e.w], 1);
    int b0 = atomicAdd(&ncnt[n.x], 1);
    int b1 = atomicAdd(&ncnt[n.y], 1);
    int b2 = atomicAdd(&ncnt[n.z], 1);
    int b3 = atomicAdd(&ncnt[n.w], 1);
    *(int4*)&r_e[j] = make_int4(a0, a1, a2, a3);
    *(int4*)&r_n[j] = make_int4(b0, b1, b2, b3);
  } else {
    for (int k = j; k < nnz; ++k) {
      r_e[k] = atomicAdd(&ecnt[edge_idx[k]], 1);
      r_n[k] = atomicAdd(&ncnt[node_idx[k]], 1);
    }
  }
}

// ---------------------------------------------------------------------------
// Two-level exclusive scan
// ---------------------------------------------------------------------------
__global__ __launch_bounds__(1024) void scan_block_kernel(
    const int* __restrict__ cnt, int* __restrict__ off,
    int* __restrict__ partials, int nbins)
{
  __shared__ int ws[16];
  int tid = threadIdx.x, lane = tid & 63, wid = tid >> 6;
  int base = blockIdx.x * 4096 + tid * 4;
  int x0 = base + 0 < nbins ? cnt[base + 0] : 0;
  int x1 = base + 1 < nbins ? cnt[base + 1] : 0;
  int x2 = base + 2 < nbins ? cnt[base + 2] : 0;
  int x3 = base + 3 < nbins ? cnt[base + 3] : 0;
  int t = x0 + x1 + x2 + x3;
  int v = t;
#pragma unroll
  for (int d = 1; d < 64; d <<= 1) {
    int y = __shfl_up(v, d, 64);
    if (lane >= d) v += y;
  }
  if (lane == 63) ws[wid] = v;
  __syncthreads();
  if (tid < 16) {
    int s = ws[tid];
#pragma unroll
    for (int d = 1; d < 16; d <<= 1) {
      int y = __shfl_up(s, d, 16);
      if (tid >= d) s += y;
    }
    ws[tid] = s;
  }
  __syncthreads();
  int pre = (wid > 0 ? ws[wid - 1] : 0) + (v - t);
  if (base + 0 < nbins) off[base + 0] = pre;
  if (base + 1 < nbins) off[base + 1] = pre + x0;
  if (base + 2 < nbins) off[base + 2] = pre + x0 + x1;
  if (base + 3 < nbins) off[base + 3] = pre + x0 + x1 + x2;
  if (tid == 0) partials[blockIdx.x] = ws[15];
}

__global__ __launch_bounds__(64) void scan_partials_kernel(
    int* __restrict__ partials, int nb)
{
  int lane = threadIdx.x;
  int t = lane < nb ? partials[lane] : 0;
  int v = t;
#pragma unroll
  for (int d = 1; d < 64; d <<= 1) {
    int y = __shfl_up(v, d, 64);
    if (lane >= d) v += y;
  }
  if (lane < nb) partials[lane] = v - t;
  if (lane == 63) partials[nb] = v;
}

__global__ void add_off_kernel(int* __restrict__ off,
                               const int* __restrict__ partials,
                               int nbins, int nb)
{
  int i = blockIdx.x * blockDim.x + threadIdx.x;
  if (i < nbins) off[i] += partials[i >> 12];
  if (i == 0) off[nbins] = partials[nb];
}

// ---------------------------------------------------------------------------
// Merged atomic-free CSR scatter (both orderings), 4 items/thread.
// ---------------------------------------------------------------------------
__global__ void scatter_kernel(const int* __restrict__ node_idx,
                               const int* __restrict__ edge_idx,
                               const int* __restrict__ r_e,
                               const int* __restrict__ r_n,
                               const int* __restrict__ eoff,
                               const int* __restrict__ noff,
                               int* __restrict__ nd_e,
                               int* __restrict__ eidx_n, int nnz)
{
  int j = (blockIdx.x * blockDim.x + threadIdx.x) * 4;
  if (j >= nnz) return;
  if (j + 4 <= nnz) {
    int4 e = *(const int4*)&edge_idx[j];
    int4 n = *(const int4*)&node_idx[j];
    int4 re = *(const int4*)&r_e[j];
    int4 rn = *(const int4*)&r_n[j];
    int p0 = eoff[e.x] + re.x, p1 = eoff[e.y] + re.y;
    int p2 = eoff[e.z] + re.z, p3 = eoff[e.w] + re.w;
    int q0 = noff[n.x] + rn.x, q1 = noff[n.y] + rn.y;
    int q2 = noff[n.z] + rn.z, q3 = noff[n.w] + rn.w;
    nd_e[p0] = n.x; nd_e[p1] = n.y; nd_e[p2] = n.z; nd_e[p3] = n.w;
    eidx_n[q0] = e.x; eidx_n[q1] = e.y; eidx_n[q2] = e.z; eidx_n[q3] = e.w;
  } else {
    for (int k = j; k < nnz; ++k) {
      int e = edge_idx[k], n = node_idx[k];
      nd_e[eoff[e] + r_e[k]] = n;
      eidx_n[noff[n] + r_n[k]] = e;
    }
  }
}

// ---------------------------------------------------------------------------
// Per-node softmax stats + weighted degree:
// ns2[n] = {s_n, lz = m + log(den + 1e-16)};  Dinv[n] = 1/sum hw
// ---------------------------------------------------------------------------
__global__ void softstat_kernel(const int* __restrict__ noff,
                                const int* __restrict__ eidx_n,
                                const float* __restrict__ s_n,
                                const float2* __restrict__ se_hw,
                                float2* __restrict__ ns2,
                                float* __restrict__ Dinv, int N_)
{
  int n = blockIdx.x * blockDim.x + threadIdx.x;
  if (n >= N_) return;
  int s = noff[n], e1 = noff[n + 1];
  float sn = s_n[n];
  float m = -INFINITY, den = 0.0f, d = 0.0f;
  int t = s;
  for (; t + 4 <= e1; t += 4) {
    int i0 = eidx_n[t], i1 = eidx_n[t + 1], i2 = eidx_n[t + 2], i3 = eidx_n[t + 3];
    float2 g0 = se_hw[i0], g1 = se_hw[i1], g2 = se_hw[i2], g3 = se_hw[i3];
    float l0 = lrelu(sn + g0.x), l1 = lrelu(sn + g1.x);
    float l2 = lrelu(sn + g2.x), l3 = lrelu(sn + g3.x);
    float mm = fmaxf(fmaxf(fmaxf(l0, l1), fmaxf(l2, l3)), m);
    den = den * __expf(m - mm) + __expf(l0 - mm) + __expf(l1 - mm)
        + __expf(l2 - mm) + __expf(l3 - mm);
    m = mm;
    d += g0.y + g1.y + g2.y + g3.y;
  }
  for (; t < e1; ++t) {
    float2 g = se_hw[eidx_n[t]];
    float l = lrelu(sn + g.x);
    float mm = fmaxf(l, m);
    den = den * __expf(m - mm) + __expf(l - mm);
    m = mm;
    d += g.y;
  }
  if (s == e1) m = 0.0f;
  float2 r;
  r.x = sn;
  r.y = m + __logf(den + 1e-16f);
  ns2[n] = r;
  Dinv[n] = d > 0.0f ? 1.0f / d : 0.0f;
}

// ---------------------------------------------------------------------------
// msg1: eo_bf16[e,:] = (1/|e|) * sum_{j in e} alpha_j * xt_bf16[nd_j,:]
// one wave per edge; 8x unrolled; alpha = exp(lrelu(s_n+s_e) - lz)
// ---------------------------------------------------------------------------
__global__ __launch_bounds__(256) void msg1_kernel(
    const int* __restrict__ eoff, const int* __restrict__ nd_e,
    const float2* __restrict__ ns2, const float* __restrict__ s_e,
    const ushort* __restrict__ xt, uint* __restrict__ eo, int M_)
{
  int e = blockIdx.x * (blockDim.x >> 6) + (threadIdx.x >> 6);
  int lane = threadIdx.x & 63;
  if (e >= M_) return;
  int s = eoff[e], t1 = eoff[e + 1];
  int len = t1 - s;
  float binv = len > 0 ? 1.0f / (float)len : 0.0f;
  float se = s_e[e];
  const uint* xt4 = (const uint*)xt + lane;
  float2 acc = {0.0f, 0.0f};
  int t = s;
  for (; t + 8 <= t1; t += 8) {
    int n0 = nd_e[t],     n1 = nd_e[t + 1], n2 = nd_e[t + 2], n3 = nd_e[t + 3];
    int n4 = nd_e[t + 4], n5 = nd_e[t + 5], n6 = nd_e[t + 6], n7 = nd_e[t + 7];
    float2 q0 = ns2[n0], q1 = ns2[n1], q2 = ns2[n2], q3 = ns2[n3];
    float2 q4 = ns2[n4], q5 = ns2[n5], q6 = ns2[n6], q7 = ns2[n7];
    uint u0 = xt4[(size_t)n0 * 64], u1 = xt4[(size_t)n1 * 64];
    uint u2 = xt4[(size_t)n2 * 64], u3 = xt4[(size_t)n3 * 64];
    uint u4 = xt4[(size_t)n4 * 64], u5 = xt4[(size_t)n5 * 64];
    uint u6 = xt4[(size_t)n6 * 64], u7 = xt4[(size_t)n7 * 64];
    float c0 = __expf(lrelu(q0.x + se) - q0.y);
    float c1 = __expf(lrelu(q1.x + se) - q1.y);
    float c2 = __expf(lrelu(q2.x + se) - q2.y);
    float c3 = __expf(lrelu(q3.x + se) - q3.y);
    float c4 = __expf(lrelu(q4.x + se) - q4.y);
    float c5 = __expf(lrelu(q5.x + se) - q5.y);
    float c6 = __expf(lrelu(q6.x + se) - q6.y);
    float c7 = __expf(lrelu(q7.x + se) - q7.y);
    acc.x = fmaf(c0, bf_lo(u0), acc.x); acc.y = fmaf(c0, bf_hi(u0), acc.y);
    acc.x = fmaf(c1, bf_lo(u1), acc.x); acc.y = fmaf(c1, bf_hi(u1), acc.y);
    acc.x = fmaf(c2, bf_lo(u2), acc.x); acc.y = fmaf(c2, bf_hi(u2), acc.y);
    acc.x = fmaf(c3, bf_lo(u3), acc.x); acc.y = fmaf(c3, bf_hi(u3), acc.y);
    acc.x = fmaf(c4, bf_lo(u4), acc.x); acc.y = fmaf(c4, bf_hi(u4), acc.y);
    acc.x = fmaf(c5, bf_lo(u5), acc.x); acc.y = fmaf(c5, bf_hi(u5), acc.y);
    acc.x = fmaf(c6, bf_lo(u6), acc.x); acc.y = fmaf(c6, bf_hi(u6), acc.y);
    acc.x = fmaf(c7, bf_lo(u7), acc.x); acc.y = fmaf(c7, bf_hi(u7), acc.y);
  }
  for (; t < t1; ++t) {
    int nd = nd_e[t];
    float2 q = ns2[nd];
    uint u = xt4[(size_t)nd * 64];
    float c = __expf(lrelu(q.x + se) - q.y);
    acc.x = fmaf(c, bf_lo(u), acc.x);
    acc.y = fmaf(c, bf_hi(u), acc.y);
  }
  eo[(size_t)e * (DIM / 2) + lane] = pack_bf2(acc.x * binv, acc.y * binv);
}

// ---------------------------------------------------------------------------
// msg2 fused with residual + stack accumulation. One wave per node; 8x unroll.
// ---------------------------------------------------------------------------
__global__ __launch_bounds__(256) void msg2_kernel(
    const int* __restrict__ noff, const int* __restrict__ eidx_n,
    const float2* __restrict__ ns2, const float* __restrict__ Dinv,
    const float* __restrict__ s_e, const uint* __restrict__ eo,
    const float* __restrict__ bias, float* __restrict__ cur,
    float* __restrict__ dout, int N_)
{
  int n = blockIdx.x * (blockDim.x >> 6) + (threadIdx.x >> 6);
  int lane = threadIdx.x & 63;
  if (n >= N_) return;
  int s = noff[n], t1 = noff[n + 1];
  float2 ns = ns2[n];
  float sn = ns.x, lz = ns.y;
  const uint* eo4 = eo + lane;
  float2 acc = {0.0f, 0.0f};
  int t = s;
  for (; t + 8 <= t1; t += 8) {
    int e0 = eidx_n[t],     e1 = eidx_n[t + 1], e2 = eidx_n[t + 2], e3 = eidx_n[t + 3];
    int e4 = eidx_n[t + 4], e5 = eidx_n[t + 5], e6 = eidx_n[t + 6], e7 = eidx_n[t + 7];
    float x0 = s_e[e0], x1 = s_e[e1], x2 = s_e[e2], x3 = s_e[e3];
    float x4 = s_e[e4], x5 = s_e[e5], x6 = s_e[e6], x7 = s_e[e7];
    uint u0 = eo4[(size_t)e0 * 64], u1 = eo4[(size_t)e1 * 64];
    uint u2 = eo4[(size_t)e2 * 64], u3 = eo4[(size_t)e3 * 64];
    uint u4 = eo4[(size_t)e4 * 64], u5 = eo4[(size_t)e5 * 64];
    uint u6 = eo4[(size_t)e6 * 64], u7 = eo4[(size_t)e7 * 64];
    float c0 = __expf(lrelu(sn + x0) - lz);
    float c1 = __expf(lrelu(sn + x1) - lz);
    float c2 = __expf(lrelu(sn + x2) - lz);
    float c3 = __expf(lrelu(sn + x3) - lz);
    float c4 = __expf(lrelu(sn + x4) - lz);
    float c5 = __expf(lrelu(sn + x5) - lz);
    float c6 = __expf(lrelu(sn + x6) - lz);
    float c7 = __expf(lrelu(sn + x7) - lz);
    acc.x = fmaf(c0, bf_lo(u0), acc.x); acc.y = fmaf(c0, bf_hi(u0), acc.y);
    acc.x = fmaf(c1, bf_lo(u1), acc.x); acc.y = fmaf(c1, bf_hi(u1), acc.y);
    acc.x = fmaf(c2, bf_lo(u2), acc.x); acc.y = fmaf(c2, bf_hi(u2), acc.y);
    acc.x = fmaf(c3, bf_lo(u3), acc.x); acc.y = fmaf(c3, bf_hi(u3), acc.y);
    acc.x = fmaf(c4, bf_lo(u4), acc.x); acc.y = fmaf(c4, bf_hi(u4), acc.y);
    acc.x = fmaf(c5, bf_lo(u5), acc.x); acc.y = fmaf(c5, bf_hi(u5), acc.y);
    acc.x = fmaf(c6, bf_lo(u6), acc.x); acc.y = fmaf(c6, bf_hi(u6), acc.y);
    acc.x = fmaf(c7, bf_lo(u7), acc.x); acc.y = fmaf(c7, bf_hi(u7), acc.y);
  }
  for (; t < t1; ++t) {
    int e = eidx_n[t];
    uint u = eo4[(size_t)e * 64];
    float c = __expf(lrelu(sn + s_e[e]) - lz);
    acc.x = fmaf(c, bf_lo(u), acc.x);
    acc.y = fmaf(c, bf_hi(u), acc.y);
  }
  float sc = Dinv[n];
  float2 b = ((const float2*)bias)[lane];
  size_t idx = (size_t)n * DIM + lane * 2;
  float cx = cur[idx], cy = cur[idx + 1];
  cx += acc.x * sc + b.x;
  cy += acc.y * sc + b.y;
  cur[idx] = cx; cur[idx + 1] = cy;
  dout[idx] += cx; dout[idx + 1] += cy;
}

// ---------------------------------------------------------------------------
__global__ void initcopy_kernel(const float4* __restrict__ p,
                                float4* __restrict__ cur, float4* __restrict__ dout,
                                int n4)
{
  int i = blockIdx.x * blockDim.x + threadIdx.x;
  if (i >= n4) return;
  float4 v = p[i];
  cur[i] = v;
  dout[i] = v;
}

__global__ void scale_kernel(float4* __restrict__ dout, int n4)
{
  int i = blockIdx.x * blockDim.x + threadIdx.x;
  if (i >= n4) return;
  float4 v = dout[i];
  v.x *= 0.25f; v.y *= 0.25f; v.z *= 0.25f; v.w *= 0.25f;
  dout[i] = v;
}

// ---------------------------------------------------------------------------
static inline int cdiv(int a, int b) { return (a + b - 1) / b; }

extern "C" void kernel_launch(void* const* d_in, const int* in_sizes, int n_in,
                              void* d_out, int out_size, void* d_ws, size_t ws_size,
                              hipStream_t stream)
{
  const float* pois = (const float*)d_in[0];
  const float* traj = (const float*)d_in[1];
  const float* hw   = (const float*)d_in[2];
  const int* node_idx = (const int*)d_in[3];
  const int* edge_idx = (const int*)d_in[4];
  const float* W    = (const float*)d_in[5];
  const float* att  = (const float*)d_in[6];
  const float* bias = (const float*)d_in[7];
  float* dout = (float*)d_out;

  const int N   = in_sizes[0] / DIM;
  const int M   = in_sizes[2];
  const int NNZ = in_sizes[3];

  char* p = (char*)d_ws;
  auto alloc = [&](size_t bytes) -> void* {
    void* r = (void*)p;
    p += (bytes + 255) & ~(size_t)255;
    return r;
  };
  ushort* xt_bf = (ushort*)alloc((size_t)N * DIM * 2);
  uint*   eo_bf = (uint*)alloc((size_t)M * (DIM / 2) * 4);
  float*  cur   = (float*)alloc((size_t)N * DIM * 4);
  float2* ns2   = (float2*)alloc((size_t)N * 8);
  float*  s_e  = (float*)alloc((size_t)M * 4);
  float2* se_hw = (float2*)alloc((size_t)M * 8);
  float*  s_n  = (float*)alloc((size_t)N * 4);
  float*  Dinv = (float*)alloc((size_t)N * 4);
  int* ecnt = (int*)alloc((size_t)M * 4);
  int* ncnt = (int*)alloc((size_t)N * 4);
  int* eoff = (int*)alloc((size_t)(M + 1) * 4);
  int* noff = (int*)alloc((size_t)(N + 1) * 4);
  int* r_e  = (int*)alloc((size_t)NNZ * 4);
  int* r_n  = (int*)alloc((size_t)NNZ * 4);
  int* nd_e   = (int*)alloc((size_t)NNZ * 4);
  int* eidx_n = (int*)alloc((size_t)NNZ * 4);
  int* part_e = (int*)alloc(65 * 4);
  int* part_n = (int*)alloc(65 * 4);
  (void)ws_size;

  const int nbE = cdiv(M, 4096), nbN = cdiv(N, 4096);

  // ---- incidence structure (layer-invariant) ----
  hipMemsetAsync(ecnt, 0, (size_t)M * 4, stream);
  hipMemsetAsync(ncnt, 0, (size_t)N * 4, stream);
  hist_rank_kernel<<<cdiv(NNZ, 1024), 256, 0, stream>>>(node_idx, edge_idx, ncnt, ecnt, r_n, r_e, NNZ);
  scan_block_kernel<<<nbE, 1024, 0, stream>>>(ecnt, eoff, part_e, M);
  scan_block_kernel<<<nbN, 1024, 0, stream>>>(ncnt, noff, part_n, N);
  scan_partials_kernel<<<1, 64, 0, stream>>>(part_e, nbE);
  scan_partials_kernel<<<1, 64, 0, stream>>>(part_n, nbN);
  add_off_kernel<<<cdiv(M, 256), 256, 0, stream>>>(eoff, part_e, M, nbE);
  add_off_kernel<<<cdiv(N, 256), 256, 0, stream>>>(noff, part_n, N, nbN);
  scatter_kernel<<<cdiv(NNZ, 1024), 256, 0, stream>>>(node_idx, edge_idx, r_e, r_n, eoff, noff, nd_e, eidx_n, NNZ);

  // ---- layer-invariant dense work: s_e, se_hw ----
  se_kernel<<<cdiv(M, 4), 256, 0, stream>>>(traj, W, att, hw, s_e, se_hw, M);

  // ---- init cur / accumulator ----
  int n4 = (N * DIM) / 4;
  initcopy_kernel<<<cdiv(n4, 256), 256, 0, stream>>>((const float4*)pois, (float4*)cur, (float4*)dout, n4);

  // ---- layers ----
  for (int layer = 0; layer < 3; ++layer) {
    gemm128_kernel<<<cdiv(N, 32), 256, 0, stream>>>(cur, W, att, xt_bf, s_n, N);
    softstat_kernel<<<cdiv(N, 256), 256, 0, stream>>>(noff, eidx_n, s_n, se_hw, ns2, Dinv, N);
    msg1_kernel<<<cdiv(M, 4), 256, 0, stream>>>(eoff, nd_e, ns2, s_e, xt_bf, eo_bf, M);
    msg2_kernel<<<cdiv(N, 4), 256, 0, stream>>>(noff, eidx_n, ns2, Dinv, s_e, eo_bf, bias, cur, dout, N);
  }

  scale_kernel<<<cdiv(n4, 256), 256, 0, stream>>>((float4*)dout, n4);
}

// Round 6
// 753.705 us; speedup vs baseline: 1.1936x; 1.1936x over previous
//
#include <hip/hip_runtime.h>
#include <cstdint>
#include <cstddef>

#define DIM 128
#define NEG_SLOPE 0.2f

typedef __attribute__((ext_vector_type(8))) short short8v;
typedef __attribute__((ext_vector_type(4))) float float4v;

// ---- bf16 helpers (manual, RNE) -------------------------------------------
__device__ __forceinline__ float bf_lo(uint u) { return __uint_as_float(u << 16); }
__device__ __forceinline__ float bf_hi(uint u) { return __uint_as_float(u & 0xffff0000u); }
__device__ __forceinline__ uint f2bf(float f) {
  uint u = __float_as_uint(f);
  return (u + 0x7fffu + ((u >> 16) & 1u)) >> 16;
}
__device__ __forceinline__ uint pack_bf2(float lo, float hi) {
  return f2bf(lo) | (f2bf(hi) << 16);
}
__device__ __forceinline__ float lrelu(float x) {
  return x >= 0.0f ? x : NEG_SLOPE * x;
}

// ---------------------------------------------------------------------------
// W pre-swizzle into MFMA B-fragment order (once):
// Wswz[((kt*8+nt)*64+lane)*8 + j] = bf16(W[(kt*32+(lane>>4)*8+j)*128 + nt*16+(lane&15)])
// ---------------------------------------------------------------------------
__global__ void wswz_kernel(const float* __restrict__ W, ushort* __restrict__ Wswz)
{
  int i = blockIdx.x * 256 + threadIdx.x;   // 0..16383
  int j = i & 7, lane = (i >> 3) & 63, nt = (i >> 9) & 7, kt = i >> 12;
  int k = kt * 32 + (lane >> 4) * 8 + j;
  int col = nt * 16 + (lane & 15);
  Wswz[i] = (ushort)f2bf(W[k * 128 + col]);
}

// ---------------------------------------------------------------------------
// pois -> bf16 (padded rows zeroed)
// ---------------------------------------------------------------------------
__global__ void poisbf_kernel(const float* __restrict__ pois,
                              uint4* __restrict__ pois_bf, int N_, int NP)
{
  int i = blockIdx.x * 256 + threadIdx.x;   // each = 8 bf16 = one uint4
  if (i >= NP * 16) return;
  int row = i >> 4;
  uint4 o;
  if (row < N_) {
    const float* src = pois + (size_t)i * 8;
    float4 f0 = *(const float4*)src;
    float4 f1 = *(const float4*)(src + 4);
    o.x = pack_bf2(f0.x, f0.y); o.y = pack_bf2(f0.z, f0.w);
    o.z = pack_bf2(f1.x, f1.y); o.w = pack_bf2(f1.z, f1.w);
  } else { o.x = o.y = o.z = o.w = 0; }
  pois_bf[i] = o;
}

// ---------------------------------------------------------------------------
// MFMA GEMM: Y_bf16 = X_bf16 @ W (Wswz pre-swizzled), fused s_n epilogue.
// 256 thr = 4 waves; wave handles 16 rows x 128 cols; block = 64 rows.
// ---------------------------------------------------------------------------
__global__ __launch_bounds__(256) void gemm_mfma_kernel(
    const ushort* __restrict__ Xb, const ushort* __restrict__ Wswz,
    const float* __restrict__ att, ushort* __restrict__ Yb,
    float* __restrict__ s_n, int rowsN)
{
  __shared__ ushort st[64 * 128];
  int tid = threadIdx.x;
  int w = tid >> 6, lane = tid & 63;
  int q = lane >> 4, c = lane & 15;
  int r0b = blockIdx.x * 64;
  int r0 = r0b + w * 16;
  float4v acc[8];
#pragma unroll
  for (int nt = 0; nt < 8; ++nt) acc[nt] = (float4v){0.f, 0.f, 0.f, 0.f};
  const ushort* arow = Xb + (size_t)(r0 + c) * DIM + q * 8;
#pragma unroll
  for (int kt = 0; kt < 4; ++kt) {
    short8v a = *(const short8v*)(arow + kt * 32);
#pragma unroll
    for (int nt = 0; nt < 8; ++nt) {
      short8v b = *(const short8v*)(Wswz + ((((kt << 3) + nt) << 9) + (lane << 3)));
      acc[nt] = __builtin_amdgcn_mfma_f32_16x16x32_bf16(a, b, acc[nt], 0, 0, 0);
    }
  }
  // s_n epilogue: row m = q*4+reg, col = nt*16+c
  float av[8];
#pragma unroll
  for (int nt = 0; nt < 8; ++nt) av[nt] = att[nt * 16 + c];
  float p0 = 0, p1 = 0, p2 = 0, p3 = 0;
#pragma unroll
  for (int nt = 0; nt < 8; ++nt) {
    p0 = fmaf(acc[nt][0], av[nt], p0);
    p1 = fmaf(acc[nt][1], av[nt], p1);
    p2 = fmaf(acc[nt][2], av[nt], p2);
    p3 = fmaf(acc[nt][3], av[nt], p3);
  }
#pragma unroll
  for (int m = 8; m >= 1; m >>= 1) {
    p0 += __shfl_xor(p0, m, 64);
    p1 += __shfl_xor(p1, m, 64);
    p2 += __shfl_xor(p2, m, 64);
    p3 += __shfl_xor(p3, m, 64);
  }
  if (c == 0) {
    int rb = r0 + q * 4;
    if (rb + 0 < rowsN) s_n[rb + 0] = p0;
    if (rb + 1 < rowsN) s_n[rb + 1] = p1;
    if (rb + 2 < rowsN) s_n[rb + 2] = p2;
    if (rb + 3 < rowsN) s_n[rb + 3] = p3;
  }
  // LDS transpose for coalesced bf16 store
  ushort* sw = st + w * 2048;
#pragma unroll
  for (int nt = 0; nt < 8; ++nt) {
    sw[(q * 4 + 0) * 128 + nt * 16 + c] = (ushort)f2bf(acc[nt][0]);
    sw[(q * 4 + 1) * 128 + nt * 16 + c] = (ushort)f2bf(acc[nt][1]);
    sw[(q * 4 + 2) * 128 + nt * 16 + c] = (ushort)f2bf(acc[nt][2]);
    sw[(q * 4 + 3) * 128 + nt * 16 + c] = (ushort)f2bf(acc[nt][3]);
  }
  __syncthreads();
#pragma unroll
  for (int it = 0; it < 4; ++it) {
    int idx = tid + it * 256;           // 0..1023 x ushort8
    int row = idx >> 4, seg = idx & 15;
    *(uint4*)(Yb + (size_t)(r0b + row) * DIM + seg * 8) =
        *(const uint4*)&st[row * 128 + seg * 8];
  }
}

// ---------------------------------------------------------------------------
// se_kernel: wv2 = W @ att[D:] (per-block in LDS), s_e + se_hw pack.
// ---------------------------------------------------------------------------
__global__ __launch_bounds__(256) void se_kernel(
    const float* __restrict__ traj, const float* __restrict__ W,
    const float* __restrict__ att, const float* __restrict__ hw,
    float* __restrict__ s_e, float2* __restrict__ se_hw, int M_)
{
  __shared__ float wv[128];
  int tid = threadIdx.x;
  if (tid < 128) {
    const float* wr = W + (size_t)tid * 128;
    float acc = 0.0f;
#pragma unroll 4
    for (int k = 0; k < 128; ++k) acc = fmaf(wr[k], att[DIM + k], acc);
    wv[tid] = acc;
  }
  __syncthreads();
  int e = blockIdx.x * 4 + (tid >> 6);
  int lane = tid & 63;
  if (e >= M_) return;
  const float* row = traj + (size_t)e * DIM;
  float v = row[lane] * wv[lane] + row[lane + 64] * wv[lane + 64];
#pragma unroll
  for (int d = 32; d > 0; d >>= 1) v += __shfl_down(v, d, 64);
  if (lane == 0) {
    s_e[e] = v;
    float2 g; g.x = v; g.y = hw[e];
    se_hw[e] = g;
  }
}

// ---------------------------------------------------------------------------
// Rank-fused histogram, 2 items/thread.
// ---------------------------------------------------------------------------
__global__ void hist_rank_kernel(const int* __restrict__ node_idx,
                                 const int* __restrict__ edge_idx,
                                 int* __restrict__ ncnt, int* __restrict__ ecnt,
                                 int* __restrict__ r_n, int* __restrict__ r_e,
                                 int nnz)
{
  int j = (blockIdx.x * blockDim.x + threadIdx.x) * 2;
  if (j >= nnz) return;
  if (j + 2 <= nnz) {
    int2 e = *(const int2*)&edge_idx[j];
    int2 n = *(const int2*)&node_idx[j];
    int a0 = atomicAdd(&ecnt[e.x], 1);
    int a1 = atomicAdd(&ecnt[e.y], 1);
    int b0 = atomicAdd(&ncnt[n.x], 1);
    int b1 = atomicAdd(&ncnt[n.y], 1);
    *(int2*)&r_e[j] = make_int2(a0, a1);
    *(int2*)&r_n[j] = make_int2(b0, b1);
  } else {
    r_e[j] = atomicAdd(&ecnt[edge_idx[j]], 1);
    r_n[j] = atomicAdd(&ncnt[node_idx[j]], 1);
  }
}

// ---------------------------------------------------------------------------
// Two-level exclusive scan
// ---------------------------------------------------------------------------
__global__ __launch_bounds__(1024) void scan_block_kernel(
    const int* __restrict__ cnt, int* __restrict__ off,
    int* __restrict__ partials, int nbins)
{
  __shared__ int ws[16];
  int tid = threadIdx.x, lane = tid & 63, wid = tid >> 6;
  int base = blockIdx.x * 4096 + tid * 4;
  int x0 = base + 0 < nbins ? cnt[base + 0] : 0;
  int x1 = base + 1 < nbins ? cnt[base + 1] : 0;
  int x2 = base + 2 < nbins ? cnt[base + 2] : 0;
  int x3 = base + 3 < nbins ? cnt[base + 3] : 0;
  int t = x0 + x1 + x2 + x3;
  int v = t;
#pragma unroll
  for (int d = 1; d < 64; d <<= 1) {
    int y = __shfl_up(v, d, 64);
    if (lane >= d) v += y;
  }
  if (lane == 63) ws[wid] = v;
  __syncthreads();
  if (tid < 16) {
    int s = ws[tid];
#pragma unroll
    for (int d = 1; d < 16; d <<= 1) {
      int y = __shfl_up(s, d, 16);
      if (tid >= d) s += y;
    }
    ws[tid] = s;
  }
  __syncthreads();
  int pre = (wid > 0 ? ws[wid - 1] : 0) + (v - t);
  if (base + 0 < nbins) off[base + 0] = pre;
  if (base + 1 < nbins) off[base + 1] = pre + x0;
  if (base + 2 < nbins) off[base + 2] = pre + x0 + x1;
  if (base + 3 < nbins) off[base + 3] = pre + x0 + x1 + x2;
  if (tid == 0) partials[blockIdx.x] = ws[15];
}

__global__ __launch_bounds__(64) void scan_partials_kernel(
    int* __restrict__ partials, int nb)
{
  int lane = threadIdx.x;
  int t = lane < nb ? partials[lane] : 0;
  int v = t;
#pragma unroll
  for (int d = 1; d < 64; d <<= 1) {
    int y = __shfl_up(v, d, 64);
    if (lane >= d) v += y;
  }
  if (lane < nb) partials[lane] = v - t;
  if (lane == 63) partials[nb] = v;
}

__global__ void add_off_kernel(int* __restrict__ off,
                               const int* __restrict__ partials,
                               int nbins, int nb)
{
  int i = blockIdx.x * blockDim.x + threadIdx.x;
  if (i < nbins) off[i] += partials[i >> 12];
  if (i == 0) off[nbins] = partials[nb];
}

// ---------------------------------------------------------------------------
// SPLIT atomic-free CSR scatters (merged version write-amped L2 — round 5)
// ---------------------------------------------------------------------------
__global__ void scatter_edge_kernel(const int* __restrict__ node_idx,
                                    const int* __restrict__ edge_idx,
                                    const int* __restrict__ r_e,
                                    const int* __restrict__ eoff,
                                    int* __restrict__ nd_e, int nnz)
{
  int j = (blockIdx.x * blockDim.x + threadIdx.x) * 4;
  if (j >= nnz) return;
  if (j + 4 <= nnz) {
    int4 e = *(const int4*)&edge_idx[j];
    int4 n = *(const int4*)&node_idx[j];
    int4 re = *(const int4*)&r_e[j];
    nd_e[eoff[e.x] + re.x] = n.x;
    nd_e[eoff[e.y] + re.y] = n.y;
    nd_e[eoff[e.z] + re.z] = n.z;
    nd_e[eoff[e.w] + re.w] = n.w;
  } else {
    for (int k = j; k < nnz; ++k) nd_e[eoff[edge_idx[k]] + r_e[k]] = node_idx[k];
  }
}

__global__ void scatter_node_kernel(const int* __restrict__ node_idx,
                                    const int* __restrict__ edge_idx,
                                    const int* __restrict__ r_n,
                                    const int* __restrict__ noff,
                                    int* __restrict__ eidx_n, int nnz)
{
  int j = (blockIdx.x * blockDim.x + threadIdx.x) * 4;
  if (j >= nnz) return;
  if (j + 4 <= nnz) {
    int4 e = *(const int4*)&edge_idx[j];
    int4 n = *(const int4*)&node_idx[j];
    int4 rn = *(const int4*)&r_n[j];
    eidx_n[noff[n.x] + rn.x] = e.x;
    eidx_n[noff[n.y] + rn.y] = e.y;
    eidx_n[noff[n.z] + rn.z] = e.z;
    eidx_n[noff[n.w] + rn.w] = e.w;
  } else {
    for (int k = j; k < nnz; ++k) eidx_n[noff[node_idx[k]] + r_n[k]] = edge_idx[k];
  }
}

// ---------------------------------------------------------------------------
// Per-node softmax stats + weighted degree
// ---------------------------------------------------------------------------
__global__ void softstat_kernel(const int* __restrict__ noff,
                                const int* __restrict__ eidx_n,
                                const float* __restrict__ s_n,
                                const float2* __restrict__ se_hw,
                                float2* __restrict__ ns2,
                                float* __restrict__ Dinv, int N_)
{
  int n = blockIdx.x * blockDim.x + threadIdx.x;
  if (n >= N_) return;
  int s = noff[n], e1 = noff[n + 1];
  float sn = s_n[n];
  float m = -INFINITY, den = 0.0f, d = 0.0f;
  int t = s;
  for (; t + 4 <= e1; t += 4) {
    int i0 = eidx_n[t], i1 = eidx_n[t + 1], i2 = eidx_n[t + 2], i3 = eidx_n[t + 3];
    float2 g0 = se_hw[i0], g1 = se_hw[i1], g2 = se_hw[i2], g3 = se_hw[i3];
    float l0 = lrelu(sn + g0.x), l1 = lrelu(sn + g1.x);
    float l2 = lrelu(sn + g2.x), l3 = lrelu(sn + g3.x);
    float mm = fmaxf(fmaxf(fmaxf(l0, l1), fmaxf(l2, l3)), m);
    den = den * __expf(m - mm) + __expf(l0 - mm) + __expf(l1 - mm)
        + __expf(l2 - mm) + __expf(l3 - mm);
    m = mm;
    d += g0.y + g1.y + g2.y + g3.y;
  }
  for (; t < e1; ++t) {
    float2 g = se_hw[eidx_n[t]];
    float l = lrelu(sn + g.x);
    float mm = fmaxf(l, m);
    den = den * __expf(m - mm) + __expf(l - mm);
    m = mm;
    d += g.y;
  }
  if (s == e1) m = 0.0f;
  float2 r;
  r.x = sn;
  r.y = m + __logf(den + 1e-16f);
  ns2[n] = r;
  Dinv[n] = d > 0.0f ? 1.0f / d : 0.0f;
}

// ---------------------------------------------------------------------------
// msg1: one wave per edge; 8x unrolled gather MLP
// ---------------------------------------------------------------------------
__global__ __launch_bounds__(256) void msg1_kernel(
    const int* __restrict__ eoff, const int* __restrict__ nd_e,
    const float2* __restrict__ ns2, const float* __restrict__ s_e,
    const ushort* __restrict__ xt, uint* __restrict__ eo, int M_)
{
  int e = blockIdx.x * (blockDim.x >> 6) + (threadIdx.x >> 6);
  int lane = threadIdx.x & 63;
  if (e >= M_) return;
  int s = eoff[e], t1 = eoff[e + 1];
  int len = t1 - s;
  float binv = len > 0 ? 1.0f / (float)len : 0.0f;
  float se = s_e[e];
  const uint* xt4 = (const uint*)xt + lane;
  float2 acc = {0.0f, 0.0f};
  int t = s;
  for (; t + 8 <= t1; t += 8) {
    int n0 = nd_e[t],     n1 = nd_e[t + 1], n2 = nd_e[t + 2], n3 = nd_e[t + 3];
    int n4 = nd_e[t + 4], n5 = nd_e[t + 5], n6 = nd_e[t + 6], n7 = nd_e[t + 7];
    float2 q0 = ns2[n0], q1 = ns2[n1], q2 = ns2[n2], q3 = ns2[n3];
    float2 q4 = ns2[n4], q5 = ns2[n5], q6 = ns2[n6], q7 = ns2[n7];
    uint u0 = xt4[(size_t)n0 * 64], u1 = xt4[(size_t)n1 * 64];
    uint u2 = xt4[(size_t)n2 * 64], u3 = xt4[(size_t)n3 * 64];
    uint u4 = xt4[(size_t)n4 * 64], u5 = xt4[(size_t)n5 * 64];
    uint u6 = xt4[(size_t)n6 * 64], u7 = xt4[(size_t)n7 * 64];
    float c0 = __expf(lrelu(q0.x + se) - q0.y);
    float c1 = __expf(lrelu(q1.x + se) - q1.y);
    float c2 = __expf(lrelu(q2.x + se) - q2.y);
    float c3 = __expf(lrelu(q3.x + se) - q3.y);
    float c4 = __expf(lrelu(q4.x + se) - q4.y);
    float c5 = __expf(lrelu(q5.x + se) - q5.y);
    float c6 = __expf(lrelu(q6.x + se) - q6.y);
    float c7 = __expf(lrelu(q7.x + se) - q7.y);
    acc.x = fmaf(c0, bf_lo(u0), acc.x); acc.y = fmaf(c0, bf_hi(u0), acc.y);
    acc.x = fmaf(c1, bf_lo(u1), acc.x); acc.y = fmaf(c1, bf_hi(u1), acc.y);
    acc.x = fmaf(c2, bf_lo(u2), acc.x); acc.y = fmaf(c2, bf_hi(u2), acc.y);
    acc.x = fmaf(c3, bf_lo(u3), acc.x); acc.y = fmaf(c3, bf_hi(u3), acc.y);
    acc.x = fmaf(c4, bf_lo(u4), acc.x); acc.y = fmaf(c4, bf_hi(u4), acc.y);
    acc.x = fmaf(c5, bf_lo(u5), acc.x); acc.y = fmaf(c5, bf_hi(u5), acc.y);
    acc.x = fmaf(c6, bf_lo(u6), acc.x); acc.y = fmaf(c6, bf_hi(u6), acc.y);
    acc.x = fmaf(c7, bf_lo(u7), acc.x); acc.y = fmaf(c7, bf_hi(u7), acc.y);
  }
  for (; t < t1; ++t) {
    int nd = nd_e[t];
    float2 q = ns2[nd];
    uint u = xt4[(size_t)nd * 64];
    float c = __expf(lrelu(q.x + se) - q.y);
    acc.x = fmaf(c, bf_lo(u), acc.x);
    acc.y = fmaf(c, bf_hi(u), acc.y);
  }
  eo[(size_t)e * (DIM / 2) + lane] = pack_bf2(acc.x * binv, acc.y * binv);
}

// ---------------------------------------------------------------------------
// msg2 fused: residual + stack accumulation + (layer0: init from pois) +
// (last layer: *0.25 final) + bf16 mirror of cur for the MFMA gemm.
// ---------------------------------------------------------------------------
__global__ __launch_bounds__(256) void msg2_kernel(
    const int* __restrict__ noff, const int* __restrict__ eidx_n,
    const float2* __restrict__ ns2, const float* __restrict__ Dinv,
    const float* __restrict__ s_e, const uint* __restrict__ eo,
    const float* __restrict__ bias,
    const float* __restrict__ cur_in, const float* __restrict__ acc_in,
    float* __restrict__ cur_out, uint* __restrict__ curbf_out,
    float* __restrict__ acc_out, int last, int N_)
{
  int n = blockIdx.x * (blockDim.x >> 6) + (threadIdx.x >> 6);
  int lane = threadIdx.x & 63;
  if (n >= N_) return;
  int s = noff[n], t1 = noff[n + 1];
  float2 nsv = ns2[n];
  float sn = nsv.x, lz = nsv.y;
  const uint* eo4 = eo + lane;
  float2 acc = {0.0f, 0.0f};
  int t = s;
  for (; t + 8 <= t1; t += 8) {
    int e0 = eidx_n[t],     e1 = eidx_n[t + 1], e2 = eidx_n[t + 2], e3 = eidx_n[t + 3];
    int e4 = eidx_n[t + 4], e5 = eidx_n[t + 5], e6 = eidx_n[t + 6], e7 = eidx_n[t + 7];
    float x0 = s_e[e0], x1 = s_e[e1], x2 = s_e[e2], x3 = s_e[e3];
    float x4 = s_e[e4], x5 = s_e[e5], x6 = s_e[e6], x7 = s_e[e7];
    uint u0 = eo4[(size_t)e0 * 64], u1 = eo4[(size_t)e1 * 64];
    uint u2 = eo4[(size_t)e2 * 64], u3 = eo4[(size_t)e3 * 64];
    uint u4 = eo4[(size_t)e4 * 64], u5 = eo4[(size_t)e5 * 64];
    uint u6 = eo4[(size_t)e6 * 64], u7 = eo4[(size_t)e7 * 64];
    float c0 = __expf(lrelu(sn + x0) - lz);
    float c1 = __expf(lrelu(sn + x1) - lz);
    float c2 = __expf(lrelu(sn + x2) - lz);
    float c3 = __expf(lrelu(sn + x3) - lz);
    float c4 = __expf(lrelu(sn + x4) - lz);
    float c5 = __expf(lrelu(sn + x5) - lz);
    float c6 = __expf(lrelu(sn + x6) - lz);
    float c7 = __expf(lrelu(sn + x7) - lz);
    acc.x = fmaf(c0, bf_lo(u0), acc.x); acc.y = fmaf(c0, bf_hi(u0), acc.y);
    acc.x = fmaf(c1, bf_lo(u1), acc.x); acc.y = fmaf(c1, bf_hi(u1), acc.y);
    acc.x = fmaf(c2, bf_lo(u2), acc.x); acc.y = fmaf(c2, bf_hi(u2), acc.y);
    acc.x = fmaf(c3, bf_lo(u3), acc.x); acc.y = fmaf(c3, bf_hi(u3), acc.y);
    acc.x = fmaf(c4, bf_lo(u4), acc.x); acc.y = fmaf(c4, bf_hi(u4), acc.y);
    acc.x = fmaf(c5, bf_lo(u5), acc.x); acc.y = fmaf(c5, bf_hi(u5), acc.y);
    acc.x = fmaf(c6, bf_lo(u6), acc.x); acc.y = fmaf(c6, bf_hi(u6), acc.y);
    acc.x = fmaf(c7, bf_lo(u7), acc.x); acc.y = fmaf(c7, bf_hi(u7), acc.y);
  }
  for (; t < t1; ++t) {
    int e = eidx_n[t];
    uint u = eo4[(size_t)e * 64];
    float c = __expf(lrelu(sn + s_e[e]) - lz);
    acc.x = fmaf(c, bf_lo(u), acc.x);
    acc.y = fmaf(c, bf_hi(u), acc.y);
  }
  float sc = Dinv[n];
  float2 b = ((const float2*)bias)[lane];
  size_t idx = (size_t)n * DIM + lane * 2;
  float cx = cur_in[idx]     + acc.x * sc + b.x;
  float cy = cur_in[idx + 1] + acc.y * sc + b.y;
  if (last) {
    acc_out[idx]     = (acc_in[idx]     + cx) * 0.25f;
    acc_out[idx + 1] = (acc_in[idx + 1] + cy) * 0.25f;
  } else {
    cur_out[idx] = cx; cur_out[idx + 1] = cy;
    curbf_out[(size_t)n * 64 + lane] = pack_bf2(cx, cy);
    acc_out[idx]     = acc_in[idx]     + cx;
    acc_out[idx + 1] = acc_in[idx + 1] + cy;
  }
}

// ---------------------------------------------------------------------------
static inline int cdiv(int a, int b) { return (a + b - 1) / b; }

extern "C" void kernel_launch(void* const* d_in, const int* in_sizes, int n_in,
                              void* d_out, int out_size, void* d_ws, size_t ws_size,
                              hipStream_t stream)
{
  const float* pois = (const float*)d_in[0];
  const float* traj = (const float*)d_in[1];
  const float* hw   = (const float*)d_in[2];
  const int* node_idx = (const int*)d_in[3];
  const int* edge_idx = (const int*)d_in[4];
  const float* W    = (const float*)d_in[5];
  const float* att  = (const float*)d_in[6];
  const float* bias = (const float*)d_in[7];
  float* dout = (float*)d_out;

  const int N   = in_sizes[0] / DIM;
  const int M   = in_sizes[2];
  const int NNZ = in_sizes[3];
  const int NP  = (N + 63) & ~63;   // row-padded for 64-row MFMA tiles

  char* p = (char*)d_ws;
  auto alloc = [&](size_t bytes) -> void* {
    void* r = (void*)p;
    p += (bytes + 255) & ~(size_t)255;
    return r;
  };
  ushort* xt_bf   = (ushort*)alloc((size_t)NP * DIM * 2);
  ushort* cur_bf  = (ushort*)alloc((size_t)NP * DIM * 2);
  ushort* pois_bf = (ushort*)alloc((size_t)NP * DIM * 2);
  ushort* W_swz   = (ushort*)alloc(16384 * 2);
  uint*   eo_bf = (uint*)alloc((size_t)M * (DIM / 2) * 4);
  float*  cur   = (float*)alloc((size_t)N * DIM * 4);
  float2* ns2   = (float2*)alloc((size_t)N * 8);
  float*  s_e  = (float*)alloc((size_t)M * 4);
  float2* se_hw = (float2*)alloc((size_t)M * 8);
  float*  s_n  = (float*)alloc((size_t)N * 4);
  float*  Dinv = (float*)alloc((size_t)N * 4);
  int* ecnt = (int*)alloc((size_t)M * 4);
  int* ncnt = (int*)alloc((size_t)N * 4);
  int* eoff = (int*)alloc((size_t)(M + 1) * 4);
  int* noff = (int*)alloc((size_t)(N + 1) * 4);
  int* r_e  = (int*)alloc((size_t)NNZ * 4);
  int* r_n  = (int*)alloc((size_t)NNZ * 4);
  int* nd_e   = (int*)alloc((size_t)NNZ * 4);
  int* eidx_n = (int*)alloc((size_t)NNZ * 4);
  int* part_e = (int*)alloc(65 * 4);
  int* part_n = (int*)alloc(65 * 4);
  (void)ws_size;

  const int nbE = cdiv(M, 4096), nbN = cdiv(N, 4096);

  // ---- incidence structure (layer-invariant) ----
  hipMemsetAsync(ecnt, 0, (size_t)M * 4, stream);
  hipMemsetAsync(ncnt, 0, (size_t)N * 4, stream);
  hist_rank_kernel<<<cdiv(NNZ, 512), 256, 0, stream>>>(node_idx, edge_idx, ncnt, ecnt, r_n, r_e, NNZ);
  scan_block_kernel<<<nbE, 1024, 0, stream>>>(ecnt, eoff, part_e, M);
  scan_block_kernel<<<nbN, 1024, 0, stream>>>(ncnt, noff, part_n, N);
  scan_partials_kernel<<<1, 64, 0, stream>>>(part_e, nbE);
  scan_partials_kernel<<<1, 64, 0, stream>>>(part_n, nbN);
  add_off_kernel<<<cdiv(M, 256), 256, 0, stream>>>(eoff, part_e, M, nbE);
  add_off_kernel<<<cdiv(N, 256), 256, 0, stream>>>(noff, part_n, N, nbN);
  scatter_edge_kernel<<<cdiv(NNZ, 1024), 256, 0, stream>>>(node_idx, edge_idx, r_e, eoff, nd_e, NNZ);
  scatter_node_kernel<<<cdiv(NNZ, 1024), 256, 0, stream>>>(node_idx, edge_idx, r_n, noff, eidx_n, NNZ);

  // ---- layer-invariant dense prep ----
  wswz_kernel<<<64, 256, 0, stream>>>(W, W_swz);
  se_kernel<<<cdiv(M, 4), 256, 0, stream>>>(traj, W, att, hw, s_e, se_hw, M);
  poisbf_kernel<<<cdiv(NP * 16, 256), 256, 0, stream>>>(pois, (uint4*)pois_bf, N, NP);

  // ---- layers ----
  for (int layer = 0; layer < 3; ++layer) {
    const ushort* gin = (layer == 0) ? pois_bf : cur_bf;
    gemm_mfma_kernel<<<NP / 64, 256, 0, stream>>>(gin, W_swz, att, xt_bf, s_n, N);
    softstat_kernel<<<cdiv(N, 256), 256, 0, stream>>>(noff, eidx_n, s_n, se_hw, ns2, Dinv, N);
    msg1_kernel<<<cdiv(M, 4), 256, 0, stream>>>(eoff, nd_e, ns2, s_e, xt_bf, eo_bf, M);
    const float* cin = (layer == 0) ? pois : cur;
    const float* ain = (layer == 0) ? pois : dout;
    int last = (layer == 2) ? 1 : 0;
    msg2_kernel<<<cdiv(N, 4), 256, 0, stream>>>(noff, eidx_n, ns2, Dinv, s_e, eo_bf,
                                                bias, cin, ain, cur, (uint*)cur_bf,
                                                dout, last, N);
  }
}